// Round 13
// baseline (27.835 us; speedup 1.0000x reference)
//
#include <hip/hip_runtime.h>
#include <hip/hip_bf16.h>

typedef __attribute__((ext_vector_type(8))) short short8;
typedef __attribute__((ext_vector_type(4))) float f32x4;

#define NQ 32      // queries
#define NM 32      // query tokens
#define NH 128     // head dim
#define ND 512     // docs
#define NN 180     // doc tokens
#define NTMAX 12   // max compacted n-tiles (192 rows)

#define QFRAG_BYTES (NQ * 2 * 4 * 64 * 16)              // 256 KB
#define DCBLK_BYTES (NTMAX * 4 * 64 * 16)               // 49152 B per doc
#define DC_OFF      QFRAG_BYTES
#define CNT_OFF     (DC_OFF + ND * DCBLK_BYTES)         // ~25.4 MB total

static __device__ __forceinline__ unsigned short f2bf(float x) {
  __hip_bfloat16 h = __float2bfloat16(x);
  return __builtin_bit_cast(unsigned short, h);
}

static __device__ __forceinline__ uint4 pack8m(const float* v, float m) {
  unsigned int a = (unsigned)f2bf(v[0] * m) | ((unsigned)f2bf(v[1] * m) << 16);
  unsigned int b = (unsigned)f2bf(v[2] * m) | ((unsigned)f2bf(v[3] * m) << 16);
  unsigned int c = (unsigned)f2bf(v[4] * m) | ((unsigned)f2bf(v[5] * m) << 16);
  unsigned int e = (unsigned)f2bf(v[6] * m) | ((unsigned)f2bf(v[7] * m) << 16);
  return make_uint4(a, b, c, e);
}

static __device__ __forceinline__ uint4 pack8(float4 a, float4 b) {
  unsigned int x = (unsigned)f2bf(a.x) | ((unsigned)f2bf(a.y) << 16);
  unsigned int y = (unsigned)f2bf(a.z) | ((unsigned)f2bf(a.w) << 16);
  unsigned int z = (unsigned)f2bf(b.x) | ((unsigned)f2bf(b.y) << 16);
  unsigned int u = (unsigned)f2bf(b.z) | ((unsigned)f2bf(b.w) << 16);
  return make_uint4(x, y, z, u);
}

// Fragment layout (16x16x32 bf16, swapped operands): element (lane,j) of tile
// (t, ks) = M[t*16 + (lane&15)][ks*32 + (lane>>4)*8 + j], stored 16B/lane.
//
// prep: blocks 0..1023   = (doc, half) -> compaction map (ballot prefix-scan,
//                          computed redundantly in both halves), then this
//                          half's compacted bf16 frag tiles (nt = half, half+2,
//                          ...). XCD-aligned: d = ((b>>4)<<3)|(b&7) so the
//                          writer's XCD == maxsim reader's XCD (d%8).
//        blocks 1024..1087 = Q fragments (masked bf16).
__global__ __launch_bounds__(256) void prep_kernel(
    const float* __restrict__ Q, const float* __restrict__ D,
    const int* __restrict__ qmask, const int* __restrict__ dmask,
    unsigned short* __restrict__ Qb, char* __restrict__ Dc,
    int* __restrict__ cnt_arr) {
  const int tid = threadIdx.x;

  if (blockIdx.x < 2 * ND) {
    // ---------------- per-(doc,half) compaction + frag write ----------------
    __shared__ unsigned short mapinv[192];
    __shared__ int wtot[3];
    const int b = blockIdx.x;
    const int d    = ((b >> 4) << 3) | (b & 7);
    const int half = (b >> 3) & 1;
    const int lane = tid & 63;
    const int w = tid >> 6;

    int flag = 0, pre = 0;
    if (tid < NN) flag = dmask[d * NN + tid];
    if (tid < 192) {
      unsigned long long bal = __ballot(flag != 0);
      pre = __popcll(bal & ((1ull << lane) - 1ull));
      if (lane == 63) wtot[w] = pre + (flag ? 1 : 0);
    }
    __syncthreads();
    const int cnt = wtot[0] + wtot[1] + wtot[2];
    if (tid < 192 && flag) {
      int base = (w >= 1 ? wtot[0] : 0) + (w >= 2 ? wtot[1] : 0);
      mapinv[pre + base] = (unsigned short)tid;
    }
    __syncthreads();

    const int ntc = (cnt + 15) >> 4;
    uint4* dcout = reinterpret_cast<uint4*>(Dc + (size_t)d * DCBLK_BYTES);
    // this half's tiles: one 16B frag-lane slot per thread per tile
    const int ks = (tid >> 6) & 3, ln = tid & 63;
    const int bl = ln & 15, bg = ln >> 4;
    for (int nt = half; nt < ntc; nt += 2) {
      int dr = nt * 16 + bl;
      uint4 o = make_uint4(0u, 0u, 0u, 0u);
      if (dr < cnt) {
        int sr = mapinv[dr];
        const float4* p = reinterpret_cast<const float4*>(D) +
                          (size_t)(d * NN + sr) * 32 + ks * 8 + bg * 2;
        o = pack8(p[0], p[1]);
      }
      dcout[(size_t)nt * 256 + ks * 64 + ln] = o;
    }
    if (tid == 0 && half == 0) cnt_arr[d] = cnt;
  } else {
    // ---------------- Q fragments ----------------
    int idx = (blockIdx.x - 2 * ND) * 256 + tid;   // 16384 fragment-lanes
    int lane = idx & 63;
    int ks = (idx >> 6) & 3;
    int mt = (idx >> 8) & 1;
    int q  = idx >> 9;
    int row = mt * 16 + (lane & 15);
    int k0  = ks * 32 + (lane >> 4) * 8;
    const float* src = Q + (q * NM + row) * NH + k0;
    float v[8];
    *reinterpret_cast<float4*>(&v[0]) = *reinterpret_cast<const float4*>(src);
    *reinterpret_cast<float4*>(&v[4]) = *reinterpret_cast<const float4*>(src + 4);
    float m = (float)qmask[q * NM + row];
    reinterpret_cast<uint4*>(Qb)[idx] = pack8m(v, m);
  }
}

// maxsim: 2048 blocks x 256 thr (4 waves), barrier-free, LDS-free, and now
// SOFTWARE-PIPELINED: 3 Da buffers (static names, rule #20), loads issued 2
// tiles ahead so the ~200cy L2 latency hides under 2 tiles of MFMA+fold
// (R12's unroll-1 loop serialized load->MFMA->fold: ~26% per-wave MFMA duty).
// block b -> doc d = ((b>>5)<<3)|(b&7) (same XCD as prep writer: Dc L2-hot),
// wave w owns query pair q0 = (((b>>3)&3)*4 + w)*2.
// ~145 VGPR, capped 168 by __launch_bounds__(256,3) -> 3 waves/SIMD.
__global__ __launch_bounds__(256, 3) void maxsim_kernel(
    const char* __restrict__ Dc, const int* __restrict__ cnt_arr,
    const unsigned short* __restrict__ Qb, float* __restrict__ out) {
  const int b = blockIdx.x;
  const int d = ((b >> 5) << 3) | (b & 7);
  const int ps = (b >> 3) & 3;
  const int tid = threadIdx.x;
  const int lane = tid & 63;
  const int w = tid >> 6;
  const int bg = lane >> 4;
  const float NEG = -__builtin_inff();

  const int cnt = cnt_arr[d];
  const int q0 = (ps * 4 + w) * 2;

  // Q fragments for this wave's pair (64 VGPR), coalesced 16B/lane
  short8 Qf[2][2][4];  // [qi][mt][ks]
  #pragma unroll
  for (int qi = 0; qi < 2; ++qi)
    #pragma unroll
    for (int mt = 0; mt < 2; ++mt)
      #pragma unroll
      for (int ks = 0; ks < 4; ++ks)
        Qf[qi][mt][ks] = *reinterpret_cast<const short8*>(
            reinterpret_cast<const char*>(Qb) +
            ((((q0 + qi) * 2 + mt) * 4 + ks) << 10) + (lane << 4));

  float run[2][2];
  #pragma unroll
  for (int qi = 0; qi < 2; ++qi)
    #pragma unroll
    for (int mt = 0; mt < 2; ++mt) run[qi][mt] = NEG;

  const char* Dcd = Dc + (size_t)d * DCBLK_BYTES;
  const int ntc = (cnt + 15) >> 4;

  short8 DaA[4], DaB[4], DaC[4];

#define LOADT(BUF, NT)                                                   \
  {                                                                      \
    const int _nt = (NT);                                                \
    _Pragma("unroll")                                                    \
    for (int ks = 0; ks < 4; ++ks)                                       \
      BUF[ks] = *reinterpret_cast<const short8*>(                        \
          Dcd + (((_nt * 4 + ks) << 10) + (lane << 4)));                 \
  }

#define COMPUTE(BUF, NT)                                                 \
  {                                                                      \
    const int _nt = (NT);                                                \
    f32x4 acc[2][2];                                                     \
    _Pragma("unroll")                                                    \
    for (int qi = 0; qi < 2; ++qi)                                       \
      _Pragma("unroll")                                                  \
      for (int mt = 0; mt < 2; ++mt)                                     \
        acc[qi][mt] = (f32x4){0.f, 0.f, 0.f, 0.f};                       \
    _Pragma("unroll")                                                    \
    for (int ks = 0; ks < 4; ++ks)                                       \
      _Pragma("unroll")                                                  \
      for (int qi = 0; qi < 2; ++qi)                                     \
        _Pragma("unroll")                                                \
        for (int mt = 0; mt < 2; ++mt)                                   \
          acc[qi][mt] = __builtin_amdgcn_mfma_f32_16x16x32_bf16(         \
              BUF[ks], Qf[qi][mt][ks], acc[qi][mt], 0, 0, 0);            \
    if (_nt * 16 + 16 > cnt) {                                           \
      const int rlim = cnt - _nt * 16 - bg * 4;                          \
      _Pragma("unroll")                                                  \
      for (int qi = 0; qi < 2; ++qi)                                     \
        _Pragma("unroll")                                                \
        for (int mt = 0; mt < 2; ++mt) {                                 \
          float vmax = NEG;                                              \
          _Pragma("unroll")                                              \
          for (int j = 0; j < 4; ++j) {                                  \
            float v = (j < rlim) ? acc[qi][mt][j] : NEG;                 \
            vmax = fmaxf(vmax, v);                                       \
          }                                                              \
          run[qi][mt] = fmaxf(run[qi][mt], vmax);                        \
        }                                                                \
    } else {                                                             \
      _Pragma("unroll")                                                  \
      for (int qi = 0; qi < 2; ++qi)                                     \
        _Pragma("unroll")                                                \
        for (int mt = 0; mt < 2; ++mt) {                                 \
          float vmax = fmaxf(fmaxf(acc[qi][mt][0], acc[qi][mt][1]),      \
                             fmaxf(acc[qi][mt][2], acc[qi][mt][3]));     \
          run[qi][mt] = fmaxf(run[qi][mt], vmax);                        \
        }                                                                \
    }                                                                    \
  }

  if (ntc > 0) {
    LOADT(DaA, 0);
    if (ntc > 1) LOADT(DaB, 1);
    int nt = 0;
    while (true) {
      if (nt + 2 < ntc) LOADT(DaC, nt + 2);
      COMPUTE(DaA, nt);
      if (++nt == ntc) break;
      if (nt + 2 < ntc) LOADT(DaA, nt + 2);
      COMPUTE(DaB, nt);
      if (++nt == ntc) break;
      if (nt + 2 < ntc) LOADT(DaB, nt + 2);
      COMPUTE(DaC, nt);
      if (++nt == ntc) break;
    }
  }
#undef LOADT
#undef COMPUTE

  // masked doc tokens inject an exact 0 into max_n
  if (cnt < NN) {
    #pragma unroll
    for (int qi = 0; qi < 2; ++qi)
      #pragma unroll
      for (int mt = 0; mt < 2; ++mt) run[qi][mt] = fmaxf(run[qi][mt], 0.f);
  }

  // reduction: xor16/32 max over n-quarters, xor1..8 sum over m
  #pragma unroll
  for (int qi = 0; qi < 2; ++qi) {
    float a = run[qi][0];   // m = lane&15
    float bb = run[qi][1];  // m = (lane&15)+16
    a = fmaxf(a, __shfl_xor(a, 16));
    a = fmaxf(a, __shfl_xor(a, 32));
    bb = fmaxf(bb, __shfl_xor(bb, 16));
    bb = fmaxf(bb, __shfl_xor(bb, 32));
    float s = a + bb;
    s += __shfl_xor(s, 1);
    s += __shfl_xor(s, 2);
    s += __shfl_xor(s, 4);
    s += __shfl_xor(s, 8);
    if (lane == 0) out[(q0 + qi) * ND + d] = s;
  }
}

extern "C" void kernel_launch(void* const* d_in, const int* in_sizes, int n_in,
                              void* d_out, int out_size, void* d_ws, size_t ws_size,
                              hipStream_t stream) {
  const float* Q = (const float*)d_in[0];
  const float* D = (const float*)d_in[1];
  const int* qmask = (const int*)d_in[2];
  const int* dmask = (const int*)d_in[3];
  float* out = (float*)d_out;

  unsigned short* Qb = (unsigned short*)d_ws;
  char* Dc = (char*)d_ws + DC_OFF;
  int* cnt_arr = (int*)((char*)d_ws + CNT_OFF);

  prep_kernel<<<2 * ND + 64, 256, 0, stream>>>(Q, D, qmask, dmask, Qb, Dc, cnt_arr);
  maxsim_kernel<<<2048, 256, 0, stream>>>(Dc, cnt_arr, Qb, out);
}

// Round 14
// 25.898 us; speedup vs baseline: 1.0748x; 1.0748x over previous
//
#include <hip/hip_runtime.h>
#include <hip/hip_bf16.h>

typedef __attribute__((ext_vector_type(8))) short short8;
typedef __attribute__((ext_vector_type(4))) float f32x4;

#define NQ 32      // queries
#define NM 32      // query tokens
#define NH 128     // head dim
#define ND 512     // docs
#define NN 180     // doc tokens
#define NTMAX 12   // max compacted n-tiles (192 rows)

#define QFRAG_BYTES (NQ * 2 * 4 * 64 * 16)   // 256 KB frag-ordered Q in d_ws

static __device__ __forceinline__ unsigned short f2bf(float x) {
  __hip_bfloat16 h = __float2bfloat16(x);
  return __builtin_bit_cast(unsigned short, h);
}

static __device__ __forceinline__ uint4 pack8m(const float* v, float m) {
  unsigned int a = (unsigned)f2bf(v[0] * m) | ((unsigned)f2bf(v[1] * m) << 16);
  unsigned int b = (unsigned)f2bf(v[2] * m) | ((unsigned)f2bf(v[3] * m) << 16);
  unsigned int c = (unsigned)f2bf(v[4] * m) | ((unsigned)f2bf(v[5] * m) << 16);
  unsigned int e = (unsigned)f2bf(v[6] * m) | ((unsigned)f2bf(v[7] * m) << 16);
  return make_uint4(a, b, c, e);
}

static __device__ __forceinline__ uint4 pack8(float4 a, float4 b) {
  unsigned int x = (unsigned)f2bf(a.x) | ((unsigned)f2bf(a.y) << 16);
  unsigned int y = (unsigned)f2bf(a.z) | ((unsigned)f2bf(a.w) << 16);
  unsigned int z = (unsigned)f2bf(b.x) | ((unsigned)f2bf(b.y) << 16);
  unsigned int u = (unsigned)f2bf(b.z) | ((unsigned)f2bf(b.w) << 16);
  return make_uint4(x, y, z, u);
}

// Fragment layout (16x16x32 bf16, swapped operands): element (lane,j) of tile
// (t, ks) = M[t*16 + (lane&15)][ks*32 + (lane>>4)*8 + j], stored 16B/lane.

// Qb_frag[q][mt][ks][lane][8]: MFMA-ready masked bf16 Q fragments (tiny kernel).
__global__ __launch_bounds__(256) void prep_q_frag(
    const float* __restrict__ Q, const int* __restrict__ qmask,
    unsigned short* __restrict__ Qb) {
  int idx = blockIdx.x * 256 + threadIdx.x;   // 16384 fragment-lanes
  int lane = idx & 63;
  int ks = (idx >> 6) & 3;
  int mt = (idx >> 8) & 1;
  int q  = idx >> 9;
  int row = mt * 16 + (lane & 15);
  int k0  = ks * 32 + (lane >> 4) * 8;
  const float* src = Q + (q * NM + row) * NH + k0;
  float v[8];
  *reinterpret_cast<float4*>(&v[0]) = *reinterpret_cast<const float4*>(src);
  *reinterpret_cast<float4*>(&v[4]) = *reinterpret_cast<const float4*>(src + 4);
  float m = (float)qmask[q * NM + row];
  reinterpret_cast<uint4*>(Qb)[idx] = pack8m(v, m);
}

// FUSED per-doc kernel: 512 blocks x 512 thr (8 waves), one block per doc.
//  1) compaction map (ballot prefix-scan over the 180 mask flags)
//  2) stage compacted VALID rows -> LDS as bf16 MFMA-frag tiles (pad rows = 0);
//     no Dc round-trip, no mask multiply (valid rows have mask==1), D read once
//     (~23.5 MB HBM total instead of R12's 23.5 + 13 write + 50 re-read)
//  3) each wave computes 2 query pairs SEQUENTIALLY (#pragma unroll 1 -> one
//     pair's ~104 VGPR live; cap 128 via __launch_bounds__(512,4) = 4 waves/SIMD
//     with both co-resident blocks; VGPR pool is 512/SIMD [R13 lesson])
// Masked doc tokens inject exactly 0 into max_n -> clamp once iff cnt<NN.
__global__ __launch_bounds__(512, 4) void fused_maxsim(
    const float* __restrict__ D, const int* __restrict__ dmask,
    const unsigned short* __restrict__ Qb, float* __restrict__ out) {
  __shared__ unsigned char Dlds[NTMAX * 4096];   // 49152 B frag-order tiles
  __shared__ unsigned short mapinv[192];
  __shared__ int wtot[4];
  const int d = blockIdx.x;
  const int tid = threadIdx.x;
  const int lane = tid & 63;
  const int w = tid >> 6;
  const float NEG = -__builtin_inff();

  // ---- 1) compaction map ----
  int flag = 0, pre = 0;
  if (tid < NN) flag = dmask[d * NN + tid];
  if (tid < 192) {   // waves 0..2
    unsigned long long bal = __ballot(flag != 0);
    pre = __popcll(bal & ((1ull << lane) - 1ull));
    if (lane == 63) wtot[w] = pre + (flag ? 1 : 0);
  }
  __syncthreads();
  const int cnt = wtot[0] + wtot[1] + wtot[2];
  if (tid < 192 && flag) {
    int base = (w >= 1 ? wtot[0] : 0) + (w >= 2 ? wtot[1] : 0);
    mapinv[pre + base] = (unsigned short)tid;
  }
  __syncthreads();

  // ---- 2) stage compacted bf16 frag tiles (one 16B slot per thread-iter) ----
  const int ntc = (cnt + 15) >> 4;
  for (int s = tid; s < ntc * 256; s += 512) {
    int nt = s >> 8, ks = (s >> 6) & 3, ln = s & 63;
    int bl = ln & 15, bg2 = ln >> 4;
    int dr = nt * 16 + bl;
    uint4 o = make_uint4(0u, 0u, 0u, 0u);
    if (dr < cnt) {
      int sr = mapinv[dr];
      const float4* p = reinterpret_cast<const float4*>(D) +
                        (size_t)(d * NN + sr) * 32 + ks * 8 + bg2 * 2;
      o = pack8(p[0], p[1]);
    }
    *reinterpret_cast<uint4*>(&Dlds[(size_t)s * 16]) = o;
  }
  __syncthreads();

  // ---- 3) compute: wave w owns queries w*4 .. w*4+3, two sequential pairs ----
  const int bg = lane >> 4;

  #pragma unroll 1
  for (int p = 0; p < 2; ++p) {
    const int q0 = w * 4 + p * 2;

    short8 Qf[2][2][4];  // [qi][mt][ks], 64 VGPR, coalesced 16B/lane from L2-hot Qb
    #pragma unroll
    for (int qi = 0; qi < 2; ++qi)
      #pragma unroll
      for (int mt = 0; mt < 2; ++mt)
        #pragma unroll
        for (int ks = 0; ks < 4; ++ks)
          Qf[qi][mt][ks] = *reinterpret_cast<const short8*>(
              reinterpret_cast<const char*>(Qb) +
              ((((q0 + qi) * 2 + mt) * 4 + ks) << 10) + (lane << 4));

    float run[2][2];
    #pragma unroll
    for (int qi = 0; qi < 2; ++qi)
      #pragma unroll
      for (int mt = 0; mt < 2; ++mt) run[qi][mt] = NEG;

    #pragma unroll 2
    for (int nt = 0; nt < ntc; ++nt) {
      short8 Da[4];
      #pragma unroll
      for (int ks = 0; ks < 4; ++ks)
        Da[ks] = *reinterpret_cast<const short8*>(
            &Dlds[((nt * 4 + ks) << 10) + (lane << 4)]);

      f32x4 acc[2][2];
      #pragma unroll
      for (int qi = 0; qi < 2; ++qi)
        #pragma unroll
        for (int mt = 0; mt < 2; ++mt) acc[qi][mt] = (f32x4){0.f, 0.f, 0.f, 0.f};

      #pragma unroll
      for (int ks = 0; ks < 4; ++ks)
        #pragma unroll
        for (int qi = 0; qi < 2; ++qi)
          #pragma unroll
          for (int mt = 0; mt < 2; ++mt)
            acc[qi][mt] = __builtin_amdgcn_mfma_f32_16x16x32_bf16(
                Da[ks], Qf[qi][mt][ks], acc[qi][mt], 0, 0, 0);

      if (nt * 16 + 16 > cnt) {
        // tail tile: lane holds rows nt*16 + bg*4 + j; valid iff j < rlim
        const int rlim = cnt - nt * 16 - bg * 4;
        #pragma unroll
        for (int qi = 0; qi < 2; ++qi)
          #pragma unroll
          for (int mt = 0; mt < 2; ++mt) {
            float vmax = NEG;
            #pragma unroll
            for (int j = 0; j < 4; ++j) {
              float v = (j < rlim) ? acc[qi][mt][j] : NEG;
              vmax = fmaxf(vmax, v);
            }
            run[qi][mt] = fmaxf(run[qi][mt], vmax);
          }
      } else {
        #pragma unroll
        for (int qi = 0; qi < 2; ++qi)
          #pragma unroll
          for (int mt = 0; mt < 2; ++mt) {
            float vmax = fmaxf(fmaxf(acc[qi][mt][0], acc[qi][mt][1]),
                               fmaxf(acc[qi][mt][2], acc[qi][mt][3]));
            run[qi][mt] = fmaxf(run[qi][mt], vmax);
          }
      }
    }

    // masked doc tokens inject an exact 0 into max_n
    if (cnt < NN) {
      #pragma unroll
      for (int qi = 0; qi < 2; ++qi)
        #pragma unroll
        for (int mt = 0; mt < 2; ++mt) run[qi][mt] = fmaxf(run[qi][mt], 0.f);
    }

    // reduction: xor16/32 max over n-quarters, xor1..8 sum over m
    #pragma unroll
    for (int qi = 0; qi < 2; ++qi) {
      float a = run[qi][0];   // m = lane&15
      float bb = run[qi][1];  // m = (lane&15)+16
      a = fmaxf(a, __shfl_xor(a, 16));
      a = fmaxf(a, __shfl_xor(a, 32));
      bb = fmaxf(bb, __shfl_xor(bb, 16));
      bb = fmaxf(bb, __shfl_xor(bb, 32));
      float s = a + bb;
      s += __shfl_xor(s, 1);
      s += __shfl_xor(s, 2);
      s += __shfl_xor(s, 4);
      s += __shfl_xor(s, 8);
      if (lane == 0) out[(q0 + qi) * ND + d] = s;
    }
  }
}

extern "C" void kernel_launch(void* const* d_in, const int* in_sizes, int n_in,
                              void* d_out, int out_size, void* d_ws, size_t ws_size,
                              hipStream_t stream) {
  const float* Q = (const float*)d_in[0];
  const float* D = (const float*)d_in[1];
  const int* qmask = (const int*)d_in[2];
  const int* dmask = (const int*)d_in[3];
  float* out = (float*)d_out;
  unsigned short* Qb = (unsigned short*)d_ws;   // 256 KB frag-ordered Q

  prep_q_frag<<<16384 / 256, 256, 0, stream>>>(Q, qmask, Qb);
  fused_maxsim<<<ND, 512, 0, stream>>>(D, dmask, Qb, out);
}